// Round 7
// baseline (721.298 us; speedup 1.0000x reference)
//
#include <hip/hip_runtime.h>
#include <math.h>

// Problem constants
#define B_   2
#define T_   2048
#define D_   1024
#define C_   10
#define F_   513
#define NTOK (B_ * T_)     // 4096 rows
#define LF   3078          // Fall stride = 6*F_ : [qR qI kR kI vR vI]
#define KP2  1088          // padded K for output GEMM (mult of 64)
#define OIM2 544           // Im block offset inside Rcat/MoutT (16-aligned)
#define NCH  128           // scan chunks
#define TC   (T_ / NCH)    // 16 timesteps per chunk
#define TS   4             // timesteps staged per barrier pair in scans

typedef unsigned short us16;
typedef __attribute__((ext_vector_type(8))) __bf16 bf16x8;
typedef __attribute__((ext_vector_type(4))) float  f32x4;

// Workspace layout (bytes), total ~86.4 MB. RCAT aliases TCS+SFB+WT
// (10.6 MB >= 8.9 MB needed; builders are done before scan_apply writes it).
#define O_XBF    ((size_t)0)                 // x bf16: 8,388,608
#define O_WOBF   ((size_t)8388608)           // Wo bf16: 2,097,152
#define O_TCS    ((size_t)10485760)          // Tcs bf16 1026x1024: 2,101,248
#define O_SFB    ((size_t)12587008)          // Sfb bf16 1088x1024: 2,228,224
#define O_WT     ((size_t)14815232)          // WT bf16 3x1024x1024: 6,291,456
#define O_MALLB  ((size_t)21106688)          // Mall bf16 3078x1024: 6,303,744
#define O_MOUTB  ((size_t)27410432)          // MoutT bf16 1024x1088: 2,228,224
#define O_FALL   ((size_t)29638656)          // Fall fp32 4096x3078: 50,429,952
#define O_SSCAN  ((size_t)80068608)          // scan sums fp32: 10,506,240
#define O_RCAT   O_TCS                       // Rcat bf16 4096x1088: 8,912,896

__device__ __forceinline__ us16 f2b(float f) {
    union { float f; unsigned u; } v; v.f = f;
    unsigned r = v.u + 0x7FFFu + ((v.u >> 16) & 1u);
    return (us16)(r >> 16);
}

// ---------------------------------------------------------------------------
// Mega-prep kernel: one launch does (by blockIdx range)
//   [0, 8456)            trig tables Tcs (1026x1024) then Sfb (1088x1024)
//   [8456, 11528)        transpose Wq/Wk/Wv fp32 -> WT bf16 (32x32 tiles)
//   [11528, 15624)       cvt x -> Xbf
//   [15624, 16648)       cvt Wo -> WoBf
// ---------------------------------------------------------------------------
#define NTCS (1026 * 1024)
#define NSFB (KP2 * 1024)
#define PB_TRIG  8456
#define PB_TRANS (PB_TRIG + 3072)
#define PB_CVTX  (PB_TRANS + 4096)
#define PB_END   (PB_CVTX + 1024)
__global__ void hrr_prep(const float* __restrict__ x,
                         const float* __restrict__ Wq,
                         const float* __restrict__ Wk,
                         const float* __restrict__ Wv,
                         const float* __restrict__ Wo,
                         us16* __restrict__ Tcs, us16* __restrict__ Sfb,
                         us16* __restrict__ WT,
                         us16* __restrict__ Xbf, us16* __restrict__ WoBf) {
    const int bid = blockIdx.x;
    const float w = 6.135923151542565e-3f;   // 2*pi/1024
    if (bid < PB_TRIG) {
        int idx = bid * 256 + threadIdx.x;
        if (idx < NTCS) {
            int r = idx >> 10, e = idx & 1023;
            int f = (r < F_) ? r : r - F_;
            float ang = (float)((f * e) & 1023) * w;
            Tcs[idx] = f2b((r < F_) ? cosf(ang) : -sinf(ang));
        } else if ((idx -= NTCS) < NSFB) {
            int r = idx >> 10, e = idx & 1023;
            float v = 0.f;
            if (r < F_) {
                float s = (r == 0 || r == 512) ? (1.0f / 1024.0f) : (2.0f / 1024.0f);
                v = s * cosf((float)((r * e) & 1023) * w);
            } else if (r >= OIM2 && r < OIM2 + F_) {
                int f = r - OIM2;
                float s = (f == 0 || f == 512) ? (1.0f / 1024.0f) : (2.0f / 1024.0f);
                v = -s * sinf((float)((f * e) & 1023) * w);
            }
            Sfb[idx] = f2b(v);
        }
    } else if (bid < PB_TRANS) {
        int t = bid - PB_TRIG;
        int z = t >> 10, rem = t & 1023;
        const float* W = (z == 0) ? Wq : (z == 1) ? Wk : Wv;
        us16* O = WT + (size_t)z * D_ * D_;
        __shared__ float tl[32][33];
        const int bx = (rem & 31) * 32, by = (rem >> 5) * 32;
        const int tx = threadIdx.x & 31, ty = threadIdx.x >> 5;
#pragma unroll
        for (int i = 0; i < 32; i += 8)
            tl[ty + i][tx] = W[(size_t)(by + ty + i) * D_ + bx + tx];
        __syncthreads();
#pragma unroll
        for (int i = 0; i < 32; i += 8)
            O[(size_t)(bx + ty + i) * D_ + by + tx] = f2b(tl[tx][ty + i]);
    } else if (bid < PB_CVTX) {
        int i = (bid - PB_TRANS) * 256 + threadIdx.x;
        float4 v = ((const float4*)x)[i];
        ushort4 o; o.x = f2b(v.x); o.y = f2b(v.y); o.z = f2b(v.z); o.w = f2b(v.w);
        ((ushort4*)Xbf)[i] = o;
    } else {
        int i = (bid - PB_CVTX) * 256 + threadIdx.x;
        float4 v = ((const float4*)Wo)[i];
        ushort4 o; o.x = f2b(v.x); o.y = f2b(v.y); o.z = f2b(v.z); o.w = f2b(v.w);
        ((ushort4*)WoBf)[i] = o;
    }
}

// ---------------------------------------------------------------------------
// bf16 MFMA GEMM: C(MxN) = A(MxK) @ B(NxK)^T, bf16 row-major inputs.
// TM x 128 block tile, 256 threads (2x2 waves), K-step 64 (2 MFMA k-chunks
// per barrier pair -> half the barrier drains of the K32 version), register
// prefetch of tile k+1. K mult of 64, lda/ldb mult of 8.
// M/N edges: staging rows clamp, epilogue guards. Batch via blockIdx.z.
// ---------------------------------------------------------------------------
template <bool OUT_BF16, int TM>
__global__ __launch_bounds__(256, 3)
void hrr_gemm_mfma(const us16* __restrict__ Ab, const us16* __restrict__ Bb,
                   void* __restrict__ Cv, int M, int N, int K,
                   int lda, int ldb, int ldc,
                   size_t strideA, size_t strideB, size_t strideC) {
    constexpr int NA = TM / 32;       // A staging granules (rows per granule: 32)
    constexpr int WM = TM / 2;        // wave M-tile
    constexpr int MI = WM / 16;       // A fragments per wave

    const us16* A = Ab + strideA * blockIdx.z;
    const us16* B = Bb + strideB * blockIdx.z;

    __shared__ us16 As[TM * 64];
    __shared__ us16 Bs[128 * 64];

    const int tid  = threadIdx.x;
    const int lane = tid & 63;
    const int wave = tid >> 6;
    const int wm = (wave >> 1) * WM;
    const int wn = (wave & 1) * 64;
    const int bm = blockIdx.y * TM;
    const int bn = blockIdx.x * 128;

    const int r8 = tid >> 3;          // 0..31 staging row within granule
    const int c8 = (tid & 7) * 8;     // k-offset in elements (16B granules)

    const us16* pA[NA];
#pragma unroll
    for (int g = 0; g < NA; g++) {
        int r = bm + g * 32 + r8; if (r >= M) r = M - 1;
        pA[g] = A + (size_t)r * lda + c8;
    }
    const us16* pB[4];
#pragma unroll
    for (int g = 0; g < 4; g++) {
        int r = bn + g * 32 + r8; if (r >= N) r = N - 1;
        pB[g] = B + (size_t)r * ldb + c8;
    }

    f32x4 acc[MI][4];
#pragma unroll
    for (int i = 0; i < MI; i++)
#pragma unroll
        for (int j = 0; j < 4; j++) acc[i][j] = (f32x4){0.f, 0.f, 0.f, 0.f};

    const int fr = lane & 15;
    const int kg = (lane >> 4) * 8;

    uint4 aR[NA], bR[4];
#pragma unroll
    for (int g = 0; g < NA; g++) aR[g] = *(const uint4*)(pA[g]);
#pragma unroll
    for (int g = 0; g < 4; g++)  bR[g] = *(const uint4*)(pB[g]);

    for (int k0 = 0; k0 < K; k0 += 64) {
        __syncthreads();
#pragma unroll
        for (int g = 0; g < NA; g++)
            *(uint4*)(As + (g * 32 + r8) * 64 + c8) = aR[g];
#pragma unroll
        for (int g = 0; g < 4; g++)
            *(uint4*)(Bs + (g * 32 + r8) * 64 + c8) = bR[g];
        __syncthreads();

        const int kn = k0 + 64;
        if (kn < K) {                               // prefetch next tile
#pragma unroll
            for (int g = 0; g < NA; g++) aR[g] = *(const uint4*)(pA[g] + kn);
#pragma unroll
            for (int g = 0; g < 4; g++)  bR[g] = *(const uint4*)(pB[g] + kn);
        }

#pragma unroll
        for (int kk = 0; kk < 64; kk += 32) {
            bf16x8 af[MI], bfr[4];
#pragma unroll
            for (int i = 0; i < MI; i++)
                af[i] = *(const bf16x8*)(As + (wm + i * 16 + fr) * 64 + kk + kg);
#pragma unroll
            for (int j = 0; j < 4; j++)
                bfr[j] = *(const bf16x8*)(Bs + (wn + j * 16 + fr) * 64 + kk + kg);
#pragma unroll
            for (int i = 0; i < MI; i++)
#pragma unroll
                for (int j = 0; j < 4; j++)
                    acc[i][j] = __builtin_amdgcn_mfma_f32_16x16x32_bf16(af[i], bfr[j], acc[i][j], 0, 0, 0);
        }
    }

    // epilogue: C/D layout col=lane&15, row=(lane>>4)*4+reg
    const int cl = lane & 15;
    const int rq = (lane >> 4) * 4;
#pragma unroll
    for (int i = 0; i < MI; i++) {
#pragma unroll
        for (int j = 0; j < 4; j++) {
#pragma unroll
            for (int r = 0; r < 4; r++) {
                int row = bm + wm + i * 16 + rq + r;
                int col = bn + wn + j * 16 + cl;
                if (row < M && col < N) {
                    size_t o = strideC * blockIdx.z + (size_t)row * ldc + col;
                    if (OUT_BF16) ((us16*)Cv)[o] = f2b(acc[i][j][r]);
                    else          ((float*)Cv)[o] = acc[i][j][r];
                }
            }
        }
    }
}

// ---------------------------------------------------------------------------
// Scan phase 1: chunk sums. Grid (NCH, B_, 2) f-halves, 256 threads.
// TS=4 timesteps staged per barrier pair (8 barriers/block instead of 32,
// 4x the staging MLP). z=0 owns f=tid; z=1 owns f=256+tid (+512 on t0).
// ---------------------------------------------------------------------------
__global__ __launch_bounds__(256, 3)
void hrr_scan_sums(const float* __restrict__ Fall, const int* __restrict__ perms,
                   float* __restrict__ S) {
    const int n = blockIdx.x, b = blockIdx.y, half = blockIdx.z;
    const int tid = threadIdx.x;
    const int f0 = half * 256;
    const int VL = half ? 257 : 256;
    __shared__ float kR[TS][F_], kI[TS][F_], vR[TS][257], vI[TS][257];

    float aR[2][C_], aI[2][C_];
    int gg[2][C_];
#pragma unroll
    for (int i = 0; i < 2; i++) {
        const int f = (i == 0) ? (f0 + tid) : 512;
        const bool act = (i == 0) || (half == 1 && tid == 0);
#pragma unroll
        for (int c = 0; c < C_; c++) {
            gg[i][c] = act ? perms[c * F_ + f] : 0;
            aR[i][c] = aI[i][c] = 0.f;
        }
    }

    for (int t0 = 0; t0 < TC; t0 += TS) {
        __syncthreads();
#pragma unroll
        for (int t4 = 0; t4 < TS; t4++) {
            const float* row = Fall + (size_t)(b * T_ + n * TC + t0 + t4) * LF;
            for (int j = tid; j < F_; j += 256) {
                kR[t4][j] = row[2 * F_ + j]; kI[t4][j] = row[3 * F_ + j];
            }
            for (int j = tid; j < VL; j += 256) {
                vR[t4][j] = row[4 * F_ + f0 + j]; vI[t4][j] = row[5 * F_ + f0 + j];
            }
        }
        __syncthreads();
#pragma unroll
        for (int t4 = 0; t4 < TS; t4++) {
#pragma unroll
            for (int i = 0; i < 2; i++) {
                const int lv = (i == 0) ? tid : 256;
                if (i == 0 || (half == 1 && tid == 0)) {
                    float br = vR[t4][lv], bi = vI[t4][lv];
#pragma unroll
                    for (int c = 0; c < C_; c++) {
                        float ar = kR[t4][gg[i][c]], ai = kI[t4][gg[i][c]];
                        aR[i][c] += ar * br - ai * bi;
                        aI[i][c] += ar * bi + ai * br;
                    }
                }
            }
        }
    }
#pragma unroll
    for (int i = 0; i < 2; i++) {
        const int f = (i == 0) ? (f0 + tid) : 512;
        if (i == 0 || (half == 1 && tid == 0)) {
#pragma unroll
            for (int c = 0; c < C_; c++) {
                size_t a = ((((size_t)c * B_ + b) * NCH + n) * F_ + f) * 2;
                S[a] = aR[i][c]; S[a + 1] = aI[i][c];
            }
        }
    }
}

// ---------------------------------------------------------------------------
// Scan phase 2: exclusive prefix over chunks, per (c,b,f). 8-way unrolled.
// ---------------------------------------------------------------------------
__global__ void hrr_scan_prefix(float* __restrict__ S) {
    int tid = blockIdx.x * 256 + threadIdx.x;
    if (tid >= C_ * B_ * F_) return;
    int c = tid / (B_ * F_);
    int r = tid % (B_ * F_);
    int b = r / F_, f = r % F_;
    size_t base = (((size_t)c * B_ + b) * NCH) * F_ + f;
    float runR = 0.f, runI = 0.f;
    for (int n0 = 0; n0 < NCH; n0 += 8) {
        float tR[8], tI[8];
#pragma unroll
        for (int u = 0; u < 8; u++) {
            size_t a = (base + (size_t)(n0 + u) * F_) * 2;
            tR[u] = S[a]; tI[u] = S[a + 1];
        }
#pragma unroll
        for (int u = 0; u < 8; u++) {
            size_t a = (base + (size_t)(n0 + u) * F_) * 2;
            S[a] = runR; S[a + 1] = runI;
            runR += tR[u]; runI += tI[u];
        }
    }
}

// ---------------------------------------------------------------------------
// Scan phase 3: running kv in regs, r = mean_c kv*conj(fqp) -> Rcat (bf16).
// Grid (NCH, B_, 2) f-halves; TS=2 timesteps staged per barrier pair
// (q,k full + v half = 41 KB at TS=2 -> 3 blocks/CU).
// half==0 blocks zero the pad columns (513..543, 1057..1087).
// ---------------------------------------------------------------------------
#define TSA 2
__global__ __launch_bounds__(256, 3)
void hrr_scan_apply(const float* __restrict__ Fall, const int* __restrict__ perms,
                    const float* __restrict__ S, us16* __restrict__ Rcat) {
    const int n = blockIdx.x, b = blockIdx.y, half = blockIdx.z;
    const int tid = threadIdx.x;
    const int f0 = half * 256;
    const int VL = half ? 257 : 256;
    __shared__ float qR[TSA][F_], qI[TSA][F_], kR[TSA][F_], kI[TSA][F_];
    __shared__ float vR[TSA][257], vI[TSA][257];

    float kvR[2][C_], kvI[2][C_];
    int gg[2][C_];
#pragma unroll
    for (int i = 0; i < 2; i++) {
        const int f = (i == 0) ? (f0 + tid) : 512;
        const bool act = (i == 0) || (half == 1 && tid == 0);
#pragma unroll
        for (int c = 0; c < C_; c++) {
            gg[i][c] = act ? perms[c * F_ + f] : 0;
            if (act) {
                size_t a = ((((size_t)c * B_ + b) * NCH + n) * F_ + f) * 2;
                kvR[i][c] = S[a]; kvI[i][c] = S[a + 1];
            } else { kvR[i][c] = 0.f; kvI[i][c] = 0.f; }
        }
    }

    for (int t0 = 0; t0 < TC; t0 += TSA) {
        __syncthreads();
#pragma unroll
        for (int t4 = 0; t4 < TSA; t4++) {
            const float* row = Fall + (size_t)(b * T_ + n * TC + t0 + t4) * LF;
            for (int j = tid; j < F_; j += 256) {
                qR[t4][j] = row[j];           qI[t4][j] = row[F_ + j];
                kR[t4][j] = row[2 * F_ + j];  kI[t4][j] = row[3 * F_ + j];
            }
            for (int j = tid; j < VL; j += 256) {
                vR[t4][j] = row[4 * F_ + f0 + j]; vI[t4][j] = row[5 * F_ + f0 + j];
            }
        }
        __syncthreads();
#pragma unroll
        for (int t4 = 0; t4 < TSA; t4++) {
            us16* out = Rcat + (size_t)(b * T_ + n * TC + t0 + t4) * KP2;
#pragma unroll
            for (int i = 0; i < 2; i++) {
                const int f = (i == 0) ? (f0 + tid) : 512;
                const int lv = (i == 0) ? tid : 256;
                if (i == 0 || (half == 1 && tid == 0)) {
                    float vr = vR[t4][lv], vi = vI[t4][lv];
                    float accR = 0.f, accI = 0.f;
#pragma unroll
                    for (int c = 0; c < C_; c++) {
                        int g = gg[i][c];
                        float ar = kR[t4][g], ai = kI[t4][g];
                        float nR = kvR[i][c] + ar * vr - ai * vi;
                        float nI = kvI[i][c] + ar * vi + ai * vr;
                        kvR[i][c] = nR; kvI[i][c] = nI;
                        float qr = qR[t4][g], qi = qI[t4][g];
                        accR += nR * qr + nI * qi;
                        accI += nI * qr - nR * qi;
                    }
                    out[f]        = f2b(accR * 0.1f);   // 1/C
                    out[OIM2 + f] = f2b(accI * 0.1f);
                }
            }
            if (half == 0 && tid < 31) {                // zero pad columns
                out[F_ + tid] = 0;                      // 513..543
                out[OIM2 + F_ + tid] = 0;               // 1057..1087
            }
        }
    }
}

// ---------------------------------------------------------------------------
extern "C" void kernel_launch(void* const* d_in, const int* in_sizes, int n_in,
                              void* d_out, int out_size, void* d_ws, size_t ws_size,
                              hipStream_t stream) {
    const float* x  = (const float*)d_in[0];
    const float* Wq = (const float*)d_in[1];
    const float* Wk = (const float*)d_in[2];
    const float* Wv = (const float*)d_in[3];
    const float* Wo = (const float*)d_in[4];
    const int* perms = (const int*)d_in[5];
    float* out = (float*)d_out;

    char* ws = (char*)d_ws;
    us16* Xbf   = (us16*)(ws + O_XBF);
    us16* WoBf  = (us16*)(ws + O_WOBF);
    us16* Tcs   = (us16*)(ws + O_TCS);
    us16* Sfb   = (us16*)(ws + O_SFB);
    us16* WT    = (us16*)(ws + O_WT);
    us16* MallB = (us16*)(ws + O_MALLB);
    us16* MoutB = (us16*)(ws + O_MOUTB);
    us16* Rcat  = (us16*)(ws + O_RCAT);
    float* Fall = (float*)(ws + O_FALL);
    float* Ssc  = (float*)(ws + O_SSCAN);

    // one prep launch: trig + transposes + bf16 converts
    hrr_prep<<<PB_END, 256, 0, stream>>>(x, Wq, Wk, Wv, Wo, Tcs, Sfb, WT, Xbf, WoBf);

    // builder 1: Mall_w(1026x1024) = Tcs @ WT_w^T, bf16 out, batched over w
    hrr_gemm_mfma<true, 128><<<dim3(8, 9, 3), 256, 0, stream>>>(
        Tcs, WT, MallB, 1026, 1024, 1024, 1024, 1024, 1024,
        0, (size_t)D_ * D_, (size_t)1026 * 1024);

    // builder 2: MoutT(1024x1088) = WoBf @ Sfb^T, bf16 out
    hrr_gemm_mfma<true, 128><<<dim3(9, 8, 1), 256, 0, stream>>>(
        WoBf, Sfb, MoutB, 1024, KP2, 1024, 1024, 1024, KP2, 0, 0, 0);

    // main GEMM: Fall(4096x3078 fp32) = Xbf @ MallB^T
    hrr_gemm_mfma<false, 128><<<dim3(25, 32, 1), 256, 0, stream>>>(
        Xbf, MallB, Fall, NTOK, LF, 1024, 1024, 1024, LF, 0, 0, 0);

    // chunked causal scan (scan_apply zeroes Rcat pad columns itself)
    hrr_scan_sums<<<dim3(NCH, B_, 2), 256, 0, stream>>>(Fall, perms, Ssc);
    hrr_scan_prefix<<<(C_ * B_ * F_ + 255) / 256, 256, 0, stream>>>(Ssc);
    hrr_scan_apply<<<dim3(NCH, B_, 2), 256, 0, stream>>>(Fall, perms, Ssc, Rcat);

    // output GEMM: out(4096x1024 fp32) = Rcat(4096x1088) @ MoutB^T, 64-row tiles
    hrr_gemm_mfma<false, 64><<<dim3(8, 64, 1), 256, 0, stream>>>(
        Rcat, MoutB, out, NTOK, D_, KP2, KP2, KP2, D_, 0, 0, 0);
}

// Round 8
// 484.710 us; speedup vs baseline: 1.4881x; 1.4881x over previous
//
#include <hip/hip_runtime.h>
#include <math.h>

// Problem constants
#define B_   2
#define T_   2048
#define D_   1024
#define C_   10
#define F_   513
#define NTOK (B_ * T_)     // 4096 rows
#define LF   3078          // Fall stride: [q interleaved(1026) | k(1026) | v(1026)]
#define KP2  1056          // padded K for output GEMM (cols 0..1025 used, pad 30)
#define NCH  128           // scan chunks
#define TC   (T_ / NCH)    // 16 timesteps per chunk

typedef unsigned short us16;
typedef __attribute__((ext_vector_type(8))) __bf16 bf16x8;
typedef __attribute__((ext_vector_type(4))) float  f32x4;

// Workspace layout (bytes), total ~90.4 MB (proven budget). RCAT aliases
// TCS+SFB+WT (needs 8.65 MB <= 10.55 MB; builders finish before apply writes).
#define O_XBF    ((size_t)0)                 // x bf16: 8,388,608
#define O_WOBF   ((size_t)8388608)           // Wo bf16: 2,097,152
#define O_TCS    ((size_t)10485760)          // Tcs bf16 1026x1024: 2,101,248
#define O_SFB    ((size_t)12587008)          // Sfb bf16 1056x1024: 2,162,688
#define O_WT     ((size_t)14749696)          // WT bf16 3x1024x1024: 6,291,456
#define O_MALLB  ((size_t)21041152)          // Mall bf16 3x1026x1024: 6,303,744
#define O_MOUTB  ((size_t)27344896)          // MoutT bf16 1024x1056: 2,162,688
#define O_FALL   ((size_t)29507584)          // Fall fp32 4096x3078: 50,429,952
#define O_SSCAN  ((size_t)79937536)          // scan sums fp32: 10,506,240
#define O_RCAT   O_TCS                       // Rcat bf16 4096x1056: 8,650,752

__device__ __forceinline__ us16 f2b(float f) {
    union { float f; unsigned u; } v; v.f = f;
    unsigned r = v.u + 0x7FFFu + ((v.u >> 16) & 1u);
    return (us16)(r >> 16);
}

// ---------------------------------------------------------------------------
// Mega-prep: one launch.
//  [0, 8328)        trig: Tcs (1026x1024, rows 2f=cos, 2f+1=-sin) then
//                   Sfb (1056x1024, rows 2f=s*cos, 2f+1=-s*sin, pads 0)
//  [8328, 11400)    transpose Wq/Wk/Wv fp32 -> WT bf16
//  [11400, 15496)   cvt x -> Xbf
//  [15496, 16520)   cvt Wo -> WoBf
// ---------------------------------------------------------------------------
#define NTCS (1026 * 1024)
#define NSFB (KP2 * 1024)
#define PB_TRIG  8328
#define PB_TRANS 11400
#define PB_CVTX  15496
#define PB_END   16520
__global__ void hrr_prep(const float* __restrict__ x,
                         const float* __restrict__ Wq,
                         const float* __restrict__ Wk,
                         const float* __restrict__ Wv,
                         const float* __restrict__ Wo,
                         us16* __restrict__ Tcs, us16* __restrict__ Sfb,
                         us16* __restrict__ WT,
                         us16* __restrict__ Xbf, us16* __restrict__ WoBf) {
    const int bid = blockIdx.x;
    const float w = 6.135923151542565e-3f;   // 2*pi/1024
    if (bid < PB_TRIG) {
        int idx = bid * 256 + threadIdx.x;
        if (idx < NTCS) {
            int r = idx >> 10, e = idx & 1023;
            int f = r >> 1;
            float ang = (float)((f * e) & 1023) * w;
            Tcs[idx] = f2b((r & 1) ? -sinf(ang) : cosf(ang));
        } else if ((idx -= NTCS) < NSFB) {
            int r = idx >> 10, e = idx & 1023;
            float v = 0.f;
            if (r < 1026) {
                int f = r >> 1;
                float s = (f == 0 || f == 512) ? (1.0f / 1024.0f) : (2.0f / 1024.0f);
                float ang = (float)((f * e) & 1023) * w;
                v = (r & 1) ? -s * sinf(ang) : s * cosf(ang);
            }
            Sfb[idx] = f2b(v);
        }
    } else if (bid < PB_TRANS) {
        int t = bid - PB_TRIG;
        int z = t >> 10, rem = t & 1023;
        const float* W = (z == 0) ? Wq : (z == 1) ? Wk : Wv;
        us16* O = WT + (size_t)z * D_ * D_;
        __shared__ float tl[32][33];
        const int bx = (rem & 31) * 32, by = (rem >> 5) * 32;
        const int tx = threadIdx.x & 31, ty = threadIdx.x >> 5;
#pragma unroll
        for (int i = 0; i < 32; i += 8)
            tl[ty + i][tx] = W[(size_t)(by + ty + i) * D_ + bx + tx];
        __syncthreads();
#pragma unroll
        for (int i = 0; i < 32; i += 8)
            O[(size_t)(bx + ty + i) * D_ + by + tx] = f2b(tl[tx][ty + i]);
    } else if (bid < PB_CVTX) {
        int i = (bid - PB_TRANS) * 256 + threadIdx.x;
        float4 v = ((const float4*)x)[i];
        ushort4 o; o.x = f2b(v.x); o.y = f2b(v.y); o.z = f2b(v.z); o.w = f2b(v.w);
        ((ushort4*)Xbf)[i] = o;
    } else {
        int i = (bid - PB_CVTX) * 256 + threadIdx.x;
        float4 v = ((const float4*)Wo)[i];
        ushort4 o; o.x = f2b(v.x); o.y = f2b(v.y); o.z = f2b(v.z); o.w = f2b(v.w);
        ((ushort4*)WoBf)[i] = o;
    }
}

// ---------------------------------------------------------------------------
// bf16 MFMA GEMM (exact R5 engine, TM-parameterized): C(MxN)=A(MxK)@B(NxK)^T.
// TM x 128 tile, 256 threads (2x2 waves), K-step 32, 16x16x32 MFMA, register
// prefetch of tile k+1. 16 KB LDS at TM=128. K mult 32, lda/ldb mult 8.
// M/N edges: staging rows clamp, epilogue guards. Batch via blockIdx.z.
// ---------------------------------------------------------------------------
template <bool OUT_BF16, int TM>
__global__ __launch_bounds__(256, 3)
void hrr_gemm_mfma(const us16* __restrict__ Ab, const us16* __restrict__ Bb,
                   void* __restrict__ Cv, int M, int N, int K,
                   int lda, int ldb, int ldc,
                   size_t strideA, size_t strideB, size_t strideC) {
    constexpr int NA = TM / 64;       // A staging granules (64 rows each)
    constexpr int WM = TM / 2;        // wave M-tile
    constexpr int MI = WM / 16;       // A fragments per wave

    const us16* A = Ab + strideA * blockIdx.z;
    const us16* B = Bb + strideB * blockIdx.z;

    __shared__ us16 As[TM * 32];
    __shared__ us16 Bs[128 * 32];

    const int tid  = threadIdx.x;
    const int lane = tid & 63;
    const int wave = tid >> 6;
    const int wm = (wave >> 1) * WM;
    const int wn = (wave & 1) * 64;
    const int bm = blockIdx.y * TM;
    const int bn = blockIdx.x * 128;

    const int r0 = tid >> 2;          // 0..63 staging row
    const int c4 = (tid & 3) * 8;     // k-offset (elements)

    const us16* pA[NA];
#pragma unroll
    for (int g = 0; g < NA; g++) {
        int r = bm + g * 64 + r0; if (r >= M) r = M - 1;
        pA[g] = A + (size_t)r * lda + c4;
    }
    const us16* pB[2];
#pragma unroll
    for (int g = 0; g < 2; g++) {
        int r = bn + g * 64 + r0; if (r >= N) r = N - 1;
        pB[g] = B + (size_t)r * ldb + c4;
    }

    f32x4 acc[MI][4];
#pragma unroll
    for (int i = 0; i < MI; i++)
#pragma unroll
        for (int j = 0; j < 4; j++) acc[i][j] = (f32x4){0.f, 0.f, 0.f, 0.f};

    const int fr = lane & 15;
    const int kg = (lane >> 4) * 8;

    uint4 aR[NA], bR[2];
#pragma unroll
    for (int g = 0; g < NA; g++) aR[g] = *(const uint4*)(pA[g]);
#pragma unroll
    for (int g = 0; g < 2; g++)  bR[g] = *(const uint4*)(pB[g]);

    for (int k0 = 0; k0 < K; k0 += 32) {
        __syncthreads();
#pragma unroll
        for (int g = 0; g < NA; g++)
            *(uint4*)(As + (g * 64 + r0) * 32 + c4) = aR[g];
#pragma unroll
        for (int g = 0; g < 2; g++)
            *(uint4*)(Bs + (g * 64 + r0) * 32 + c4) = bR[g];
        __syncthreads();

        const int kn = k0 + 32;
        if (kn < K) {                               // prefetch next tile
#pragma unroll
            for (int g = 0; g < NA; g++) aR[g] = *(const uint4*)(pA[g] + kn);
#pragma unroll
            for (int g = 0; g < 2; g++)  bR[g] = *(const uint4*)(pB[g] + kn);
        }

        bf16x8 af[MI], bfr[4];
#pragma unroll
        for (int i = 0; i < MI; i++)
            af[i] = *(const bf16x8*)(As + (wm + i * 16 + fr) * 32 + kg);
#pragma unroll
        for (int j = 0; j < 4; j++)
            bfr[j] = *(const bf16x8*)(Bs + (wn + j * 16 + fr) * 32 + kg);
#pragma unroll
        for (int i = 0; i < MI; i++)
#pragma unroll
            for (int j = 0; j < 4; j++)
                acc[i][j] = __builtin_amdgcn_mfma_f32_16x16x32_bf16(af[i], bfr[j], acc[i][j], 0, 0, 0);
    }

    // epilogue: C/D layout col=lane&15, row=(lane>>4)*4+reg
    const int cl = lane & 15;
    const int rq = (lane >> 4) * 4;
#pragma unroll
    for (int i = 0; i < MI; i++) {
#pragma unroll
        for (int j = 0; j < 4; j++) {
#pragma unroll
            for (int r = 0; r < 4; r++) {
                int row = bm + wm + i * 16 + rq + r;
                int col = bn + wn + j * 16 + cl;
                if (row < M && col < N) {
                    size_t o = strideC * blockIdx.z + (size_t)row * ldc + col;
                    if (OUT_BF16) ((us16*)Cv)[o] = f2b(acc[i][j][r]);
                    else          ((float*)Cv)[o] = acc[i][j][r];
                }
            }
        }
    }
}

// ---------------------------------------------------------------------------
// Scan phase 1: chunk sums. Grid (NCH, B_, 2) f-halves, 256 threads.
// Interleaved complex: one float2 LDS gather per (c) instead of two b32.
// z=0 owns f=tid; z=1 owns f=256+tid plus f=512 on thread 0.
// ---------------------------------------------------------------------------
__global__ __launch_bounds__(256, 4)
void hrr_scan_sums(const float* __restrict__ Fall, const int* __restrict__ perms,
                   float* __restrict__ S) {
    const int n = blockIdx.x, b = blockIdx.y, half = blockIdx.z;
    const int tid = threadIdx.x;
    const int f0 = half * 256;
    const int VL = half ? 257 : 256;
    __shared__ float2 kc[F_], vc[257];

    float aR[2][C_], aI[2][C_];
    int gg[2][C_];
#pragma unroll
    for (int i = 0; i < 2; i++) {
        const int f = (i == 0) ? (f0 + tid) : 512;
        const bool act = (i == 0) || (half == 1 && tid == 0);
#pragma unroll
        for (int c = 0; c < C_; c++) {
            gg[i][c] = act ? perms[c * F_ + f] : 0;
            aR[i][c] = aI[i][c] = 0.f;
        }
    }

    for (int tl = 0; tl < TC; tl++) {
        const float* row = Fall + (size_t)(b * T_ + n * TC + tl) * LF;
        __syncthreads();
        for (int j = tid; j < F_; j += 256)
            kc[j] = *(const float2*)(row + 1026 + 2 * j);
        for (int j = tid; j < VL; j += 256)
            vc[j] = *(const float2*)(row + 2052 + 2 * (f0 + j));
        __syncthreads();
#pragma unroll
        for (int i = 0; i < 2; i++) {
            const int lv = (i == 0) ? tid : 256;
            if (i == 0 || (half == 1 && tid == 0)) {
                float2 v = vc[lv];
#pragma unroll
                for (int c = 0; c < C_; c++) {
                    float2 k = kc[gg[i][c]];
                    aR[i][c] += k.x * v.x - k.y * v.y;
                    aI[i][c] += k.x * v.y + k.y * v.x;
                }
            }
        }
    }
#pragma unroll
    for (int i = 0; i < 2; i++) {
        const int f = (i == 0) ? (f0 + tid) : 512;
        if (i == 0 || (half == 1 && tid == 0)) {
#pragma unroll
            for (int c = 0; c < C_; c++) {
                size_t a = ((((size_t)c * B_ + b) * NCH + n) * F_ + f) * 2;
                S[a] = aR[i][c]; S[a + 1] = aI[i][c];
            }
        }
    }
}

// ---------------------------------------------------------------------------
// Scan phase 2: exclusive prefix over chunks, per (c,b,f). 8-way unrolled.
// ---------------------------------------------------------------------------
__global__ void hrr_scan_prefix(float* __restrict__ S) {
    int tid = blockIdx.x * 256 + threadIdx.x;
    if (tid >= C_ * B_ * F_) return;
    int c = tid / (B_ * F_);
    int r = tid % (B_ * F_);
    int b = r / F_, f = r % F_;
    size_t base = (((size_t)c * B_ + b) * NCH) * F_ + f;
    float runR = 0.f, runI = 0.f;
    for (int n0 = 0; n0 < NCH; n0 += 8) {
        float tR[8], tI[8];
#pragma unroll
        for (int u = 0; u < 8; u++) {
            size_t a = (base + (size_t)(n0 + u) * F_) * 2;
            tR[u] = S[a]; tI[u] = S[a + 1];
        }
#pragma unroll
        for (int u = 0; u < 8; u++) {
            size_t a = (base + (size_t)(n0 + u) * F_) * 2;
            S[a] = runR; S[a + 1] = runI;
            runR += tR[u]; runI += tI[u];
        }
    }
}

// ---------------------------------------------------------------------------
// Scan phase 3: running kv in regs, r = mean_c kv*conj(fqp) -> Rcat (bf16,
// interleaved cols 2f/2f+1, one u32 store). Grid (NCH, B_, 2) f-halves.
// Gathers: 2 float2 LDS reads per c (k[g], q[g]) instead of 4 b32.
// half==0 blocks zero the 30 pad columns.
// ---------------------------------------------------------------------------
__global__ __launch_bounds__(256, 4)
void hrr_scan_apply(const float* __restrict__ Fall, const int* __restrict__ perms,
                    const float* __restrict__ S, us16* __restrict__ Rcat) {
    const int n = blockIdx.x, b = blockIdx.y, half = blockIdx.z;
    const int tid = threadIdx.x;
    const int f0 = half * 256;
    const int VL = half ? 257 : 256;
    __shared__ float2 qc[F_], kc[F_], vc[257];

    float kvR[2][C_], kvI[2][C_];
    int gg[2][C_];
#pragma unroll
    for (int i = 0; i < 2; i++) {
        const int f = (i == 0) ? (f0 + tid) : 512;
        const bool act = (i == 0) || (half == 1 && tid == 0);
#pragma unroll
        for (int c = 0; c < C_; c++) {
            gg[i][c] = act ? perms[c * F_ + f] : 0;
            if (act) {
                size_t a = ((((size_t)c * B_ + b) * NCH + n) * F_ + f) * 2;
                kvR[i][c] = S[a]; kvI[i][c] = S[a + 1];
            } else { kvR[i][c] = 0.f; kvI[i][c] = 0.f; }
        }
    }

    for (int tl = 0; tl < TC; tl++) {
        const int tt = b * T_ + n * TC + tl;
        const float* row = Fall + (size_t)tt * LF;
        __syncthreads();
        for (int j = tid; j < F_; j += 256) {
            qc[j] = *(const float2*)(row + 2 * j);
            kc[j] = *(const float2*)(row + 1026 + 2 * j);
        }
        for (int j = tid; j < VL; j += 256)
            vc[j] = *(const float2*)(row + 2052 + 2 * (f0 + j));
        __syncthreads();
        unsigned* out32 = (unsigned*)(Rcat + (size_t)tt * KP2);
#pragma unroll
        for (int i = 0; i < 2; i++) {
            const int f = (i == 0) ? (f0 + tid) : 512;
            const int lv = (i == 0) ? tid : 256;
            if (i == 0 || (half == 1 && tid == 0)) {
                float2 v = vc[lv];
                float accR = 0.f, accI = 0.f;
#pragma unroll
                for (int c = 0; c < C_; c++) {
                    int g = gg[i][c];
                    float2 k = kc[g];
                    float nR = kvR[i][c] + k.x * v.x - k.y * v.y;
                    float nI = kvI[i][c] + k.x * v.y + k.y * v.x;
                    kvR[i][c] = nR; kvI[i][c] = nI;
                    float2 q = qc[g];
                    accR += nR * q.x + nI * q.y;
                    accI += nI * q.x - nR * q.y;
                }
                out32[f] = (unsigned)f2b(accR * 0.1f)
                         | ((unsigned)f2b(accI * 0.1f) << 16);
            }
        }
        if (half == 0 && tid < 15)                  // zero pad cols 1026..1055
            out32[513 + tid] = 0;
    }
}

// ---------------------------------------------------------------------------
extern "C" void kernel_launch(void* const* d_in, const int* in_sizes, int n_in,
                              void* d_out, int out_size, void* d_ws, size_t ws_size,
                              hipStream_t stream) {
    const float* x  = (const float*)d_in[0];
    const float* Wq = (const float*)d_in[1];
    const float* Wk = (const float*)d_in[2];
    const float* Wv = (const float*)d_in[3];
    const float* Wo = (const float*)d_in[4];
    const int* perms = (const int*)d_in[5];
    float* out = (float*)d_out;

    char* ws = (char*)d_ws;
    us16* Xbf   = (us16*)(ws + O_XBF);
    us16* WoBf  = (us16*)(ws + O_WOBF);
    us16* Tcs   = (us16*)(ws + O_TCS);
    us16* Sfb   = (us16*)(ws + O_SFB);
    us16* WT    = (us16*)(ws + O_WT);
    us16* MallB = (us16*)(ws + O_MALLB);
    us16* MoutB = (us16*)(ws + O_MOUTB);
    us16* Rcat  = (us16*)(ws + O_RCAT);
    float* Fall = (float*)(ws + O_FALL);
    float* Ssc  = (float*)(ws + O_SSCAN);

    // one prep launch: trig + transposes + bf16 converts
    hrr_prep<<<PB_END, 256, 0, stream>>>(x, Wq, Wk, Wv, Wo, Tcs, Sfb, WT, Xbf, WoBf);

    // builder 1: Mall_w(1026x1024) = Tcs @ WT_w^T, bf16 out, batched over w
    hrr_gemm_mfma<true, 128><<<dim3(8, 9, 3), 256, 0, stream>>>(
        Tcs, WT, MallB, 1026, 1024, 1024, 1024, 1024, 1024,
        0, (size_t)D_ * D_, (size_t)1026 * 1024);

    // builder 2: MoutT(1024x1056) = WoBf @ Sfb^T, bf16 out
    hrr_gemm_mfma<true, 128><<<dim3(9, 8, 1), 256, 0, stream>>>(
        WoBf, Sfb, MoutB, 1024, KP2, 1024, 1024, 1024, KP2, 0, 0, 0);

    // main GEMM: Fall(4096x3078 fp32) = Xbf @ MallB^T
    hrr_gemm_mfma<false, 128><<<dim3(25, 32, 1), 256, 0, stream>>>(
        Xbf, MallB, Fall, NTOK, LF, 1024, 1024, 1024, LF, 0, 0, 0);

    // chunked causal scan (scan_apply zeroes Rcat pad columns itself)
    hrr_scan_sums<<<dim3(NCH, B_, 2), 256, 0, stream>>>(Fall, perms, Ssc);
    hrr_scan_prefix<<<(C_ * B_ * F_ + 255) / 256, 256, 0, stream>>>(Ssc);
    hrr_scan_apply<<<dim3(NCH, B_, 2), 256, 0, stream>>>(Fall, perms, Ssc, Rcat);

    // output GEMM: out(4096x1024 fp32) = Rcat(4096x1056) @ MoutB^T, 64-row tiles
    hrr_gemm_mfma<false, 64><<<dim3(8, 64, 1), 256, 0, stream>>>(
        Rcat, MoutB, out, NTOK, D_, KP2, KP2, KP2, D_, 0, 0, 0);
}

// Round 9
// 281.020 us; speedup vs baseline: 2.5667x; 1.7248x over previous
//
#include <hip/hip_runtime.h>
#include <math.h>

// Problem constants
#define B_   2
#define T_   2048
#define D_   1024
#define C_   10
#define F_   513
#define NTOK (B_ * T_)     // 4096 rows
#define LF   3078          // Fall stride: [q interleaved(1026) | k(1026) | v(1026)]
#define KP2  1056          // padded K for output GEMM (cols 0..1025 used, pad 30)
#define NCH  128           // scan chunks
#define TC   (T_ / NCH)    // 16 timesteps per chunk

typedef unsigned short us16;
typedef __attribute__((ext_vector_type(8))) __bf16 bf16x8;
typedef __attribute__((ext_vector_type(4))) float  f32x4;

// Workspace layout (bytes) — R5's layout. RCAT aliases PREP (WT+WoBf+Tcs,
// 10.49 MB >= 8.65 MB needed; all builders finish before scan_apply writes).
#define O_XBF    ((size_t)0)                 // x bf16: 8,388,608
#define O_PREP   ((size_t)8388608)
#define O_WT     (O_PREP)                    // WT bf16 3x1024x1024: 6,291,456
#define O_WOBF   (O_PREP + 6291456)          // Wo bf16: 2,097,152
#define O_TCS    (O_PREP + 8388608)          // Tcs bf16 1026x1024: 2,101,248
#define O_RCAT   (O_PREP)                    // Rcat bf16 4096x1056: 8,650,752
#define O_SFB    (O_PREP + 10489856)         // Sfb bf16 1056x1024: 2,162,688
#define O_MALLB  (O_SFB + 2162688)           // Mall bf16 3x1026x1024: 6,303,744
#define O_MOUTB  (O_MALLB + 6303744)         // MoutT bf16 1024x1056: 2,162,688
#define O_FALL   (O_MOUTB + 2162688)         // Fall fp32 4096x3078: 50,429,952
#define O_SSCAN  (O_FALL + 50429952)         // scan sums fp32: 10,506,240

__device__ __forceinline__ us16 f2b(float f) {
    union { float f; unsigned u; } v; v.f = f;
    unsigned r = v.u + 0x7FFFu + ((v.u >> 16) & 1u);
    return (us16)(r >> 16);
}

// ---------------------------------------------------------------------------
// float -> bf16 copy-convert (vectorized by 4)
// ---------------------------------------------------------------------------
__global__ void hrr_cvt_bf16(const float* __restrict__ in, us16* __restrict__ out, int n4) {
    int i = blockIdx.x * 256 + threadIdx.x;
    if (i < n4) {
        float4 v = ((const float4*)in)[i];
        ushort4 o;
        o.x = f2b(v.x); o.y = f2b(v.y); o.z = f2b(v.z); o.w = f2b(v.w);
        ((ushort4*)out)[i] = o;
    }
}

// ---------------------------------------------------------------------------
// Transpose W (1024x1024 fp32) -> bf16, 3 matrices via blockIdx.z
// ---------------------------------------------------------------------------
__global__ void hrr_transpose_bf16(const float* __restrict__ Wq,
                                   const float* __restrict__ Wk,
                                   const float* __restrict__ Wv,
                                   us16* __restrict__ WT) {
    const float* W = (blockIdx.z == 0) ? Wq : (blockIdx.z == 1) ? Wk : Wv;
    us16* O = WT + (size_t)blockIdx.z * D_ * D_;
    __shared__ float t[32][33];
    const int bx = blockIdx.x * 32, by = blockIdx.y * 32;
    const int tx = threadIdx.x & 31, ty = threadIdx.x >> 5;   // 32 x 8
#pragma unroll
    for (int i = 0; i < 32; i += 8)
        t[ty + i][tx] = W[(size_t)(by + ty + i) * D_ + bx + tx];
    __syncthreads();
#pragma unroll
    for (int i = 0; i < 32; i += 8)
        O[(size_t)(bx + ty + i) * D_ + by + tx] = f2b(t[tx][ty + i]);
}

// ---------------------------------------------------------------------------
// Tcs (1026x1024 bf16), INTERLEAVED rows: row 2f = cos(2*pi*f*e/1024),
// row 2f+1 = -sin(2*pi*f*e/1024).
// ---------------------------------------------------------------------------
__global__ void hrr_build_tcs(us16* __restrict__ Tcs) {
    int idx = blockIdx.x * 256 + threadIdx.x;
    if (idx >= 1026 * 1024) return;
    int r = idx >> 10, e = idx & 1023;
    int f = r >> 1;
    float ang = (float)((f * e) & 1023) * 6.135923151542565e-3f;   // 2*pi/1024
    Tcs[idx] = f2b((r & 1) ? -sinf(ang) : cosf(ang));
}

// ---------------------------------------------------------------------------
// Sfb (1056x1024 bf16), INTERLEAVED rows: row 2f = s_f*cos, row 2f+1 =
// -s_f*sin  (s_f = (f==0||f==512 ? 1 : 2)/1024); pad rows 1026..1055 = 0.
// ---------------------------------------------------------------------------
__global__ void hrr_build_sfb(us16* __restrict__ S) {
    int idx = blockIdx.x * 256 + threadIdx.x;
    if (idx >= KP2 * 1024) return;
    int r = idx >> 10, e = idx & 1023;
    float v = 0.f;
    if (r < 1026) {
        int f = r >> 1;
        float s = (f == 0 || f == 512) ? (1.0f / 1024.0f) : (2.0f / 1024.0f);
        float ang = (float)((f * e) & 1023) * 6.135923151542565e-3f;
        v = (r & 1) ? -s * sinf(ang) : s * cosf(ang);
    }
    S[idx] = f2b(v);
}

// ---------------------------------------------------------------------------
// bf16 MFMA GEMM (R5 engine): C(MxN) = A(MxK) @ B(NxK)^T, bf16 row-major in.
// 128x128 tile, 256 threads (2x2 waves of 64x64), K-step 32, 16x16x32 MFMA,
// register prefetch of tile k+1, 16 KB LDS. K mult 32, lda/ldb mult 8.
// M/N edges: staging rows clamp, epilogue guards. Batch via blockIdx.z.
// ---------------------------------------------------------------------------
template <bool OUT_BF16>
__global__ __launch_bounds__(256, 3)
void hrr_gemm_mfma(const us16* __restrict__ Ab, const us16* __restrict__ Bb,
                   void* __restrict__ Cv, int M, int N, int K,
                   int lda, int ldb, int ldc,
                   size_t strideA, size_t strideB, size_t strideC) {
    const us16* A = Ab + strideA * blockIdx.z;
    const us16* B = Bb + strideB * blockIdx.z;

    __shared__ us16 As[128 * 32];
    __shared__ us16 Bs[128 * 32];

    const int tid  = threadIdx.x;
    const int lane = tid & 63;
    const int wave = tid >> 6;
    const int wm = (wave >> 1) * 64;
    const int wn = (wave & 1) * 64;
    const int bm = blockIdx.y * 128;
    const int bn = blockIdx.x * 128;

    const int r0 = tid >> 2;          // 0..63 staging row
    const int c4 = (tid & 3) * 8;     // k-offset (elements)

    int rA0 = bm + r0;      if (rA0 >= M) rA0 = M - 1;
    int rA1 = bm + 64 + r0; if (rA1 >= M) rA1 = M - 1;
    int rB0 = bn + r0;      if (rB0 >= N) rB0 = N - 1;
    int rB1 = bn + 64 + r0; if (rB1 >= N) rB1 = N - 1;
    const us16* pA0 = A + (size_t)rA0 * lda + c4;
    const us16* pA1 = A + (size_t)rA1 * lda + c4;
    const us16* pB0 = B + (size_t)rB0 * ldb + c4;
    const us16* pB1 = B + (size_t)rB1 * ldb + c4;

    f32x4 acc[4][4];
#pragma unroll
    for (int i = 0; i < 4; i++)
#pragma unroll
        for (int j = 0; j < 4; j++) acc[i][j] = (f32x4){0.f, 0.f, 0.f, 0.f};

    const int fr = lane & 15;
    const int kg = (lane >> 4) * 8;

    uint4 a0 = *(const uint4*)(pA0);
    uint4 a1 = *(const uint4*)(pA1);
    uint4 b0 = *(const uint4*)(pB0);
    uint4 b1 = *(const uint4*)(pB1);

    for (int k0 = 0; k0 < K; k0 += 32) {
        __syncthreads();
        *(uint4*)(As + r0 * 32 + c4)        = a0;
        *(uint4*)(As + (64 + r0) * 32 + c4) = a1;
        *(uint4*)(Bs + r0 * 32 + c4)        = b0;
        *(uint4*)(Bs + (64 + r0) * 32 + c4) = b1;
        __syncthreads();

        const int kn = k0 + 32;
        if (kn < K) {                               // prefetch next tile
            a0 = *(const uint4*)(pA0 + kn);
            a1 = *(const uint4*)(pA1 + kn);
            b0 = *(const uint4*)(pB0 + kn);
            b1 = *(const uint4*)(pB1 + kn);
        }

        bf16x8 af[4], bfr[4];
#pragma unroll
        for (int i = 0; i < 4; i++)
            af[i] = *(const bf16x8*)(As + (wm + i * 16 + fr) * 32 + kg);
#pragma unroll
        for (int j = 0; j < 4; j++)
            bfr[j] = *(const bf16x8*)(Bs + (wn + j * 16 + fr) * 32 + kg);
#pragma unroll
        for (int i = 0; i < 4; i++)
#pragma unroll
            for (int j = 0; j < 4; j++)
                acc[i][j] = __builtin_amdgcn_mfma_f32_16x16x32_bf16(af[i], bfr[j], acc[i][j], 0, 0, 0);
    }

    // epilogue: C/D layout col=lane&15, row=(lane>>4)*4+reg
    const int cl = lane & 15;
    const int rq = (lane >> 4) * 4;
#pragma unroll
    for (int i = 0; i < 4; i++) {
#pragma unroll
        for (int j = 0; j < 4; j++) {
#pragma unroll
            for (int r = 0; r < 4; r++) {
                int row = bm + wm + i * 16 + rq + r;
                int col = bn + wn + j * 16 + cl;
                if (row < M && col < N) {
                    size_t o = strideC * blockIdx.z + (size_t)row * ldc + col;
                    if (OUT_BF16) ((us16*)Cv)[o] = f2b(acc[i][j][r]);
                    else          ((float*)Cv)[o] = acc[i][j][r];
                }
            }
        }
    }
}

// ---------------------------------------------------------------------------
// Scan phase 1: chunk sums. Grid (NCH, B_, 2) f-halves, 256 threads.
// Interleaved complex: one float2 LDS gather per c instead of two b32.
// z=0 owns f=tid; z=1 owns f=256+tid plus f=512 on thread 0.
// ---------------------------------------------------------------------------
__global__ __launch_bounds__(256, 4)
void hrr_scan_sums(const float* __restrict__ Fall, const int* __restrict__ perms,
                   float* __restrict__ S) {
    const int n = blockIdx.x, b = blockIdx.y, half = blockIdx.z;
    const int tid = threadIdx.x;
    const int f0 = half * 256;
    const int VL = half ? 257 : 256;
    __shared__ float2 kc[F_], vc[257];

    float aR[2][C_], aI[2][C_];
    int gg[2][C_];
#pragma unroll
    for (int i = 0; i < 2; i++) {
        const int f = (i == 0) ? (f0 + tid) : 512;
        const bool act = (i == 0) || (half == 1 && tid == 0);
#pragma unroll
        for (int c = 0; c < C_; c++) {
            gg[i][c] = act ? perms[c * F_ + f] : 0;
            aR[i][c] = aI[i][c] = 0.f;
        }
    }

    for (int tl = 0; tl < TC; tl++) {
        const float* row = Fall + (size_t)(b * T_ + n * TC + tl) * LF;
        __syncthreads();
        for (int j = tid; j < F_; j += 256)
            kc[j] = *(const float2*)(row + 1026 + 2 * j);
        for (int j = tid; j < VL; j += 256)
            vc[j] = *(const float2*)(row + 2052 + 2 * (f0 + j));
        __syncthreads();
#pragma unroll
        for (int i = 0; i < 2; i++) {
            const int lv = (i == 0) ? tid : 256;
            if (i == 0 || (half == 1 && tid == 0)) {
                float2 v = vc[lv];
#pragma unroll
                for (int c = 0; c < C_; c++) {
                    float2 k = kc[gg[i][c]];
                    aR[i][c] += k.x * v.x - k.y * v.y;
                    aI[i][c] += k.x * v.y + k.y * v.x;
                }
            }
        }
    }
#pragma unroll
    for (int i = 0; i < 2; i++) {
        const int f = (i == 0) ? (f0 + tid) : 512;
        if (i == 0 || (half == 1 && tid == 0)) {
#pragma unroll
            for (int c = 0; c < C_; c++) {
                size_t a = ((((size_t)c * B_ + b) * NCH + n) * F_ + f) * 2;
                S[a] = aR[i][c]; S[a + 1] = aI[i][c];
            }
        }
    }
}

// ---------------------------------------------------------------------------
// Scan phase 2: exclusive prefix over chunks, per (c,b,f). 8-way unrolled.
// ---------------------------------------------------------------------------
__global__ void hrr_scan_prefix(float* __restrict__ S) {
    int tid = blockIdx.x * 256 + threadIdx.x;
    if (tid >= C_ * B_ * F_) return;
    int c = tid / (B_ * F_);
    int r = tid % (B_ * F_);
    int b = r / F_, f = r % F_;
    size_t base = (((size_t)c * B_ + b) * NCH) * F_ + f;
    float runR = 0.f, runI = 0.f;
    for (int n0 = 0; n0 < NCH; n0 += 8) {
        float tR[8], tI[8];
#pragma unroll
        for (int u = 0; u < 8; u++) {
            size_t a = (base + (size_t)(n0 + u) * F_) * 2;
            tR[u] = S[a]; tI[u] = S[a + 1];
        }
#pragma unroll
        for (int u = 0; u < 8; u++) {
            size_t a = (base + (size_t)(n0 + u) * F_) * 2;
            S[a] = runR; S[a + 1] = runI;
            runR += tR[u]; runI += tI[u];
        }
    }
}

// ---------------------------------------------------------------------------
// Scan phase 3: running kv in regs, r = mean_c kv*conj(fqp) -> Rcat (bf16,
// interleaved cols 2f/2f+1, one packed u32 store). Grid (NCH, B_, 2).
// half==0 blocks zero the 30 pad columns.
// ---------------------------------------------------------------------------
__global__ __launch_bounds__(256, 4)
void hrr_scan_apply(const float* __restrict__ Fall, const int* __restrict__ perms,
                    const float* __restrict__ S, us16* __restrict__ Rcat) {
    const int n = blockIdx.x, b = blockIdx.y, half = blockIdx.z;
    const int tid = threadIdx.x;
    const int f0 = half * 256;
    const int VL = half ? 257 : 256;
    __shared__ float2 qc[F_], kc[F_], vc[257];

    float kvR[2][C_], kvI[2][C_];
    int gg[2][C_];
#pragma unroll
    for (int i = 0; i < 2; i++) {
        const int f = (i == 0) ? (f0 + tid) : 512;
        const bool act = (i == 0) || (half == 1 && tid == 0);
#pragma unroll
        for (int c = 0; c < C_; c++) {
            gg[i][c] = act ? perms[c * F_ + f] : 0;
            if (act) {
                size_t a = ((((size_t)c * B_ + b) * NCH + n) * F_ + f) * 2;
                kvR[i][c] = S[a]; kvI[i][c] = S[a + 1];
            } else { kvR[i][c] = 0.f; kvI[i][c] = 0.f; }
        }
    }

    for (int tl = 0; tl < TC; tl++) {
        const int tt = b * T_ + n * TC + tl;
        const float* row = Fall + (size_t)tt * LF;
        __syncthreads();
        for (int j = tid; j < F_; j += 256) {
            qc[j] = *(const float2*)(row + 2 * j);
            kc[j] = *(const float2*)(row + 1026 + 2 * j);
        }
        for (int j = tid; j < VL; j += 256)
            vc[j] = *(const float2*)(row + 2052 + 2 * (f0 + j));
        __syncthreads();
        unsigned* out32 = (unsigned*)(Rcat + (size_t)tt * KP2);
#pragma unroll
        for (int i = 0; i < 2; i++) {
            const int f = (i == 0) ? (f0 + tid) : 512;
            const int lv = (i == 0) ? tid : 256;
            if (i == 0 || (half == 1 && tid == 0)) {
                float2 v = vc[lv];
                float accR = 0.f, accI = 0.f;
#pragma unroll
                for (int c = 0; c < C_; c++) {
                    int g = gg[i][c];
                    float2 k = kc[g];
                    float nR = kvR[i][c] + k.x * v.x - k.y * v.y;
                    float nI = kvI[i][c] + k.x * v.y + k.y * v.x;
                    kvR[i][c] = nR; kvI[i][c] = nI;
                    float2 q = qc[g];
                    accR += nR * q.x + nI * q.y;
                    accI += nI * q.x - nR * q.y;
                }
                out32[f] = (unsigned)f2b(accR * 0.1f)
                         | ((unsigned)f2b(accI * 0.1f) << 16);
            }
        }
        if (half == 0 && tid < 15)                  // zero pad cols 1026..1055
            out32[513 + tid] = 0;
    }
}

// ---------------------------------------------------------------------------
extern "C" void kernel_launch(void* const* d_in, const int* in_sizes, int n_in,
                              void* d_out, int out_size, void* d_ws, size_t ws_size,
                              hipStream_t stream) {
    const float* x  = (const float*)d_in[0];
    const float* Wq = (const float*)d_in[1];
    const float* Wk = (const float*)d_in[2];
    const float* Wv = (const float*)d_in[3];
    const float* Wo = (const float*)d_in[4];
    const int* perms = (const int*)d_in[5];
    float* out = (float*)d_out;

    char* ws = (char*)d_ws;
    us16* Xbf   = (us16*)(ws + O_XBF);
    us16* WT    = (us16*)(ws + O_WT);
    us16* WoBf  = (us16*)(ws + O_WOBF);
    us16* Tcs   = (us16*)(ws + O_TCS);
    us16* Sfb   = (us16*)(ws + O_SFB);
    us16* MallB = (us16*)(ws + O_MALLB);
    us16* MoutB = (us16*)(ws + O_MOUTB);
    us16* Rcat  = (us16*)(ws + O_RCAT);
    float* Fall = (float*)(ws + O_FALL);
    float* Ssc  = (float*)(ws + O_SSCAN);

    // prep (R5 structure: separate small kernels)
    hrr_cvt_bf16<<<4096, 256, 0, stream>>>(x, Xbf, NTOK * D_ / 4);
    hrr_cvt_bf16<<<1024, 256, 0, stream>>>(Wo, WoBf, D_ * D_ / 4);
    hrr_transpose_bf16<<<dim3(32, 32, 3), 256, 0, stream>>>(Wq, Wk, Wv, WT);
    hrr_build_tcs<<<(1026 * 1024 + 255) / 256, 256, 0, stream>>>(Tcs);
    hrr_build_sfb<<<(KP2 * 1024 + 255) / 256, 256, 0, stream>>>(Sfb);

    // builder 1: Mall_w(1026x1024) = Tcs @ WT_w^T, bf16 out, batched over w
    hrr_gemm_mfma<true><<<dim3(8, 9, 3), 256, 0, stream>>>(
        Tcs, WT, MallB, 1026, 1024, 1024, 1024, 1024, 1024,
        0, (size_t)D_ * D_, (size_t)1026 * 1024);

    // builder 2: MoutT(1024x1056) = WoBf @ Sfb^T, bf16 out
    hrr_gemm_mfma<true><<<dim3(9, 8, 1), 256, 0, stream>>>(
        WoBf, Sfb, MoutB, 1024, KP2, 1024, 1024, 1024, KP2, 0, 0, 0);

    // main GEMM: Fall(4096x3078 fp32) = Xbf @ MallB^T
    hrr_gemm_mfma<false><<<dim3(25, 32, 1), 256, 0, stream>>>(
        Xbf, MallB, Fall, NTOK, LF, 1024, 1024, 1024, LF, 0, 0, 0);

    // chunked causal scan (scan_apply zeroes Rcat pad columns itself)
    hrr_scan_sums<<<dim3(NCH, B_, 2), 256, 0, stream>>>(Fall, perms, Ssc);
    hrr_scan_prefix<<<(C_ * B_ * F_ + 255) / 256, 256, 0, stream>>>(Ssc);
    hrr_scan_apply<<<dim3(NCH, B_, 2), 256, 0, stream>>>(Fall, perms, Ssc, Rcat);

    // output GEMM: out(4096x1024 fp32) = Rcat(4096x1056) @ MoutB^T
    hrr_gemm_mfma<false><<<dim3(8, 32, 1), 256, 0, stream>>>(
        Rcat, MoutB, out, NTOK, D_, KP2, KP2, KP2, D_, 0, 0, 0);
}